// Round 14
// baseline (153.458 us; speedup 1.0000x reference)
//
#include <hip/hip_runtime.h>
#include <math.h>

#define BB 4
#define CC 256
#define HWN 4096
#define NTOK 16384                 // BB*HWN
#define SCQ 0.09016844136f         // (1/sqrt(256)) * log2(e)

typedef __attribute__((ext_vector_type(8))) short short8;
typedef __attribute__((ext_vector_type(4))) float f32x4;
typedef unsigned short ushort_t;

__device__ __forceinline__ ushort_t f2bf(float f) {
    unsigned int u = __float_as_uint(f);
    unsigned int r = (u + 0x7FFFu + ((u >> 16) & 1u)) >> 16;   // RNE
    return (ushort_t)r;
}
__device__ __forceinline__ unsigned int pack2(float a, float b) {
    return (unsigned int)f2bf(a) | ((unsigned int)f2bf(b) << 16);
}
__device__ __forceinline__ float fexp2(float x) {
#if __has_builtin(__builtin_amdgcn_exp2f)
    return __builtin_amdgcn_exp2f(x);     // single v_exp_f32
#else
    return exp2f(x);
#endif
}

// ---------------------------------------------------------------------------
// wprep (verified): convert q_w (pre-scaled by SCQ) and k_w to bf16;
// zero den/nx/ny.
// ---------------------------------------------------------------------------
__global__ __launch_bounds__(256) void wprep_kernel(
    const float* __restrict__ q_w, const float* __restrict__ k_w,
    ushort_t* __restrict__ qwb, ushort_t* __restrict__ kwb,
    float* __restrict__ zbuf)
{
    int t = blockIdx.x * 256 + threadIdx.x;          // grid 64 -> 16384 threads
    float4 q4 = *(const float4*)&q_w[(size_t)t * 4];
    float4 k4 = *(const float4*)&k_w[(size_t)t * 4];
    unsigned long long qo = (unsigned long long)pack2(q4.x * SCQ, q4.y * SCQ)
                          | ((unsigned long long)pack2(q4.z * SCQ, q4.w * SCQ) << 32);
    unsigned long long ko = (unsigned long long)pack2(k4.x, k4.y)
                          | ((unsigned long long)pack2(k4.z, k4.w) << 32);
    *(unsigned long long*)&qwb[(size_t)t * 4] = qo;
    *(unsigned long long*)&kwb[(size_t)t * 4] = ko;
    zbuf[t] = 0.f; zbuf[t + NTOK] = 0.f; zbuf[t + 2 * NTOK] = 0.f;
}

// ---------------------------------------------------------------------------
// Fused projection v2 (round-12 verified, verbatim): single-barrier staging
// converts fp32->bf16 directly into transposed lsB; frag-major granule
// stores.
// ---------------------------------------------------------------------------
__global__ __launch_bounds__(256, 2) void proj_kernel(
    const float* __restrict__ feature,
    const ushort_t* __restrict__ qwb, const ushort_t* __restrict__ kwb,
    const float* __restrict__ q_bias, const float* __restrict__ k_bias,
    ushort_t* __restrict__ qb, ushort_t* __restrict__ kb)
{
    int id = blockIdx.x;
    int dh = id >> 8;            // 0..1: twin blocks 256 apart share (b,tt)
    id &= 255;
    int tt = id & 63;
    int b  = id >> 6;
    int tok0 = tt * 64;

    int t = threadIdx.x, w = t >> 6, lane = t & 63;
    int n16 = lane & 15, quad = lane >> 4;

    __shared__ ushort_t lsB[64][264];   // [tok][c 0..255] bf16, stride 264

    const float* F = feature + (size_t)(b * CC) * HWN;

    int cl = t >> 2, tg = (t & 3) * 16;

    #pragma unroll
    for (int ch = 0; ch < 4; ch++) {
        const float* src = F + (size_t)(ch * 64 + cl) * HWN + tok0 + tg;
        float4 f0 = *(const float4*)(src);
        float4 f1 = *(const float4*)(src + 4);
        float4 f2 = *(const float4*)(src + 8);
        float4 f3 = *(const float4*)(src + 12);
        int c = ch * 64 + cl;
        lsB[tg + 0][c]  = f2bf(f0.x); lsB[tg + 1][c]  = f2bf(f0.y);
        lsB[tg + 2][c]  = f2bf(f0.z); lsB[tg + 3][c]  = f2bf(f0.w);
        lsB[tg + 4][c]  = f2bf(f1.x); lsB[tg + 5][c]  = f2bf(f1.y);
        lsB[tg + 6][c]  = f2bf(f1.z); lsB[tg + 7][c]  = f2bf(f1.w);
        lsB[tg + 8][c]  = f2bf(f2.x); lsB[tg + 9][c]  = f2bf(f2.y);
        lsB[tg + 10][c] = f2bf(f2.z); lsB[tg + 11][c] = f2bf(f2.w);
        lsB[tg + 12][c] = f2bf(f3.x); lsB[tg + 13][c] = f2bf(f3.y);
        lsB[tg + 14][c] = f2bf(f3.z); lsB[tg + 15][c] = f2bf(f3.w);
    }
    __syncthreads();    // single barrier: lsB complete

    int dw0 = dh * 128 + w * 32;
    #pragma unroll
    for (int dsub = 0; dsub < 2; dsub++) {
        int d0 = dw0 + dsub * 16;
        f32x4 accq[4], acck[4];
        #pragma unroll
        for (int i = 0; i < 4; i++) {
            accq[i] = (f32x4){0.f, 0.f, 0.f, 0.f};
            acck[i] = (f32x4){0.f, 0.f, 0.f, 0.f};
        }
        #pragma unroll
        for (int kc = 0; kc < 8; kc++) {
            size_t off = (size_t)(d0 + n16) * CC + kc * 32 + quad * 8;
            short8 aq = *(const short8*)&qwb[off];
            short8 ak = *(const short8*)&kwb[off];
            #pragma unroll
            for (int tokt = 0; tokt < 4; tokt++) {
                short8 bf = *(const short8*)&lsB[tokt * 16 + n16][kc * 32 + quad * 8];
                accq[tokt] = __builtin_amdgcn_mfma_f32_16x16x32_bf16(aq, bf, accq[tokt], 0, 0, 0);
                acck[tokt] = __builtin_amdgcn_mfma_f32_16x16x32_bf16(ak, bf, acck[tokt], 0, 0, 0);
            }
        }
        float bqv[4], bkv[4];
        #pragma unroll
        for (int r = 0; r < 4; r++) {
            bqv[r] = q_bias[d0 + quad * 4 + r] * SCQ;
            bkv[r] = k_bias[d0 + quad * 4 + r];
        }
        // frag-major store indices (verified formula)
        int kcq   = d0 >> 5;
        int quadA = ((d0 >> 4) & 1) * 2 + (quad >> 1);
        int halfo = quad & 1;
        #pragma unroll
        for (int tokt = 0; tokt < 4; tokt++) {
            ushort4 oq, ok;
            oq.x = f2bf(accq[tokt][0] + bqv[0]); oq.y = f2bf(accq[tokt][1] + bqv[1]);
            oq.z = f2bf(accq[tokt][2] + bqv[2]); oq.w = f2bf(accq[tokt][3] + bqv[3]);
            ok.x = f2bf(acck[tokt][0] + bkv[0]); ok.y = f2bf(acck[tokt][1] + bkv[1]);
            ok.z = f2bf(acck[tokt][2] + bkv[2]); ok.w = f2bf(acck[tokt][3] + bkv[3]);
            int tt_tile = tt * 4 + tokt;
            size_t gbyte = (((size_t)(b * 256 + tt_tile) * 512) + kcq * 64 + quadA * 16 + n16) * 16
                           + halfo * 8;
            *(ushort4*)((char*)qb + gbyte) = oq;
            *(ushort4*)((char*)kb + gbyte) = ok;
        }
    }
}

// ---------------------------------------------------------------------------
// Attention (round-12 verified structure; TWO deltas, both compiler-managed:
// (1) #pragma unroll 2 on the round loop so the compiler can RENAME the
// kf0/kf1 buffers across iteration pairs and hoist next-round K loads under
// current-round MFMA (the manual versions of this failed — v11/v13 — so the
// renaming is left entirely to the compiler's hazard tracking);
// (2) launch_bounds(256,1) raises the VGPR cap to give it headroom.
// Addresses, math, reduction byte-identical to round 12.
// Falsifiers: VGPR ~112 unchanged => compiler declined; WRITE_SIZE >> 3MB
// => spill => revert to (256,2).
// ---------------------------------------------------------------------------
__global__ __launch_bounds__(256, 1) void attn_kernel(
    const ushort_t* __restrict__ qb, const ushort_t* __restrict__ kb,
    const float* __restrict__ flow,
    float* __restrict__ den_g, float* __restrict__ nx_g, float* __restrict__ ny_g)
{
    int id = (blockIdx.x & 7) * 128 + (blockIdx.x >> 3);   // bijective XCD swizzle
    int qt = id & 63; id >>= 6;       // 64 q-tiles of 64 rows
    int sr = id & 3;  id >>= 2;       // 4 key ranges of 1024
    int b = id;

    int t = threadIdx.x;
    int w = t >> 6, lane = t & 63;
    int n16 = lane & 15, quad = lane >> 4;

    int q0 = qt * 64;
    int s_beg = sr * 1024;

    __shared__ __align__(16) ushort_t qlds[16384];   // 32 KB: 4 q-tiles, frag-major
    __shared__ float lflow[2048];                    // 1024 vx + 1024 vy

    const float* fx = flow + (size_t)b * 2 * HWN;
    const float* fy = fx + HWN;
    #pragma unroll
    for (int i = 0; i < 4; i++) {
        lflow[t + i * 256]        = fx[s_beg + t + i * 256];
        lflow[1024 + t + i * 256] = fy[s_beg + t + i * 256];
    }

    // stage Q block (4 tiles x 512 granules x 16B = 32KB), linear copy
    {
        const char* qsrc = (const char*)qb + ((size_t)(b * 256 + (q0 >> 4)) * 512) * 16;
        char* qdst = (char*)qlds;
        #pragma unroll
        for (int i = 0; i < 8; i++)
            __builtin_amdgcn_global_load_lds(
                (const __attribute__((address_space(1))) unsigned int*)(qsrc + (i * 256 + t) * 16),
                (__attribute__((address_space(3))) unsigned int*)(qdst + (i * 256 + t) * 16),
                16, 0, 0);
    }
    __syncthreads();   // only barrier: Q + flow staged

    // K granule base for this wave's 256-key quarter
    const char* kbase = (const char*)kb
        + ((size_t)(b * 256 + (s_beg >> 4) + w * 16) * 512 + lane) * 16;
    const char* qldsb = (const char*)qlds + (size_t)lane * 16;

    float den[4], nxa[4], nya[4];
    #pragma unroll
    for (int i = 0; i < 4; i++) { den[i] = 0.f; nxa[i] = 0.f; nya[i] = 0.f; }

    #pragma unroll 2
    for (int round = 0; round < 8; round++) {
        short8 kf0[8], kf1[8];
        #pragma unroll
        for (int kc = 0; kc < 8; kc++) {
            kf0[kc] = *(const short8*)(kbase + (round * 2 + 0) * 8192 + kc * 1024);
            kf1[kc] = *(const short8*)(kbase + (round * 2 + 1) * 8192 + kc * 1024);
        }
        int klbase = w * 256 + round * 32 + quad * 4;
        f32x4 vx0 = *(const f32x4*)&lflow[klbase];
        f32x4 vx1 = *(const f32x4*)&lflow[klbase + 16];
        f32x4 vy0 = *(const f32x4*)&lflow[1024 + klbase];
        f32x4 vy1 = *(const f32x4*)&lflow[1024 + klbase + 16];

        #pragma unroll
        for (int qtl = 0; qtl < 4; qtl++) {
            f32x4 a0 = (f32x4){0.f, 0.f, 0.f, 0.f};
            f32x4 a1 = (f32x4){0.f, 0.f, 0.f, 0.f};
            #pragma unroll
            for (int kc = 0; kc < 8; kc++) {
                short8 qf = *(const short8*)(qldsb + qtl * 8192 + kc * 1024);
                a0 = __builtin_amdgcn_mfma_f32_16x16x32_bf16(kf0[kc], qf, a0, 0, 0, 0);
                a1 = __builtin_amdgcn_mfma_f32_16x16x32_bf16(kf1[kc], qf, a1, 0, 0, 0);
            }
            float d_ = 0.f, x_ = 0.f, y_ = 0.f;
            #pragma unroll
            for (int r = 0; r < 4; r++) {
                float p0 = fexp2(a0[r]);
                float p1 = fexp2(a1[r]);
                d_ += p0 + p1;
                x_ = fmaf(p0, vx0[r], x_); x_ = fmaf(p1, vx1[r], x_);
                y_ = fmaf(p0, vy0[r], y_); y_ = fmaf(p1, vy1[r], y_);
            }
            den[qtl] += d_; nxa[qtl] += x_; nya[qtl] += y_;
        }
    }

    #pragma unroll
    for (int qtl = 0; qtl < 4; qtl++) {
        float dv = den[qtl], xv = nxa[qtl], yv = nya[qtl];
        dv += __shfl_down(dv, 32); dv += __shfl_down(dv, 16);
        xv += __shfl_down(xv, 32); xv += __shfl_down(xv, 16);
        yv += __shfl_down(yv, 32); yv += __shfl_down(yv, 16);
        if (lane < 16) {
            int qrow = q0 + qtl * 16 + n16;
            int gi = b * HWN + qrow;
            atomicAdd(&den_g[gi], dv);
            atomicAdd(&nx_g[gi],  xv);
            atomicAdd(&ny_g[gi],  yv);
        }
    }
}

// ---------------------------------------------------------------------------
__global__ __launch_bounds__(256) void finalize_kernel(
    const float* __restrict__ den_g, const float* __restrict__ nx_g,
    const float* __restrict__ ny_g, float* __restrict__ out)
{
    int idx = blockIdx.x * 256 + threadIdx.x;  // b*HW + n
    int b = idx >> 12, n = idx & 4095;
    float inv = 1.0f / den_g[idx];
    out[(size_t)b * 2 * HWN + n]       = nx_g[idx] * inv;
    out[(size_t)b * 2 * HWN + HWN + n] = ny_g[idx] * inv;
}

extern "C" void kernel_launch(void* const* d_in, const int* in_sizes, int n_in,
                              void* d_out, int out_size, void* d_ws, size_t ws_size,
                              hipStream_t stream) {
    const float* feature = (const float*)d_in[0];
    const float* flow    = (const float*)d_in[1];
    const float* q_w     = (const float*)d_in[2];
    const float* q_b     = (const float*)d_in[3];
    const float* k_w     = (const float*)d_in[4];
    const float* k_b     = (const float*)d_in[5];
    float* out = (float*)d_out;

    ushort_t* qbuf = (ushort_t*)d_ws;                     // [NTOK][CC] bf16, frag-major
    ushort_t* kbuf = qbuf + (size_t)NTOK * CC;            // [NTOK][CC] bf16, frag-major
    float* den = (float*)(kbuf + (size_t)NTOK * CC);      // [NTOK]
    float* nx  = den + NTOK;
    float* ny  = nx + NTOK;
    ushort_t* qwb = (ushort_t*)(ny + NTOK);               // [CC][CC] bf16 (pre-scaled)
    ushort_t* kwb = qwb + (size_t)CC * CC;                // [CC][CC] bf16

    wprep_kernel<<<64, 256, 0, stream>>>(q_w, k_w, qwb, kwb, den);  // + zero den/nx/ny
    proj_kernel<<<512, 256, 0, stream>>>(feature, qwb, kwb, q_b, k_b, qbuf, kbuf);
    attn_kernel<<<1024, 256, 0, stream>>>(qbuf, kbuf, flow, den, nx, ny);
    finalize_kernel<<<64, 256, 0, stream>>>(den, nx, ny, out);
}

// Round 15
// 135.821 us; speedup vs baseline: 1.1299x; 1.1299x over previous
//
#include <hip/hip_runtime.h>
#include <math.h>

#define BB 4
#define CC 256
#define HWN 4096
#define NTOK 16384                 // BB*HWN
#define SCQ 0.09016844136f         // (1/sqrt(256)) * log2(e)

typedef __attribute__((ext_vector_type(8))) short short8;
typedef __attribute__((ext_vector_type(4))) float f32x4;
typedef unsigned short ushort_t;

__device__ __forceinline__ ushort_t f2bf(float f) {
    unsigned int u = __float_as_uint(f);
    unsigned int r = (u + 0x7FFFu + ((u >> 16) & 1u)) >> 16;   // RNE
    return (ushort_t)r;
}
__device__ __forceinline__ unsigned int pack2(float a, float b) {
    return (unsigned int)f2bf(a) | ((unsigned int)f2bf(b) << 16);
}
__device__ __forceinline__ float fexp2(float x) {
#if __has_builtin(__builtin_amdgcn_exp2f)
    return __builtin_amdgcn_exp2f(x);     // single v_exp_f32
#else
    return exp2f(x);
#endif
}

// ---------------------------------------------------------------------------
// wprep (verified): convert q_w (pre-scaled by SCQ) and k_w to bf16;
// zero den/nx/ny.
// ---------------------------------------------------------------------------
__global__ __launch_bounds__(256) void wprep_kernel(
    const float* __restrict__ q_w, const float* __restrict__ k_w,
    ushort_t* __restrict__ qwb, ushort_t* __restrict__ kwb,
    float* __restrict__ zbuf)
{
    int t = blockIdx.x * 256 + threadIdx.x;          // grid 64 -> 16384 threads
    float4 q4 = *(const float4*)&q_w[(size_t)t * 4];
    float4 k4 = *(const float4*)&k_w[(size_t)t * 4];
    unsigned long long qo = (unsigned long long)pack2(q4.x * SCQ, q4.y * SCQ)
                          | ((unsigned long long)pack2(q4.z * SCQ, q4.w * SCQ) << 32);
    unsigned long long ko = (unsigned long long)pack2(k4.x, k4.y)
                          | ((unsigned long long)pack2(k4.z, k4.w) << 32);
    *(unsigned long long*)&qwb[(size_t)t * 4] = qo;
    *(unsigned long long*)&kwb[(size_t)t * 4] = ko;
    zbuf[t] = 0.f; zbuf[t + NTOK] = 0.f; zbuf[t + 2 * NTOK] = 0.f;
}

// ---------------------------------------------------------------------------
// Fused projection v3 (THE ONE CHANGE THIS ROUND): re-tiled to 32-token x
// 128-d blocks, grid 1024 -> 4 blocks/CU (was 512 / 2 blocks/CU). Per-block
// staging halves (lsB[32][264] = 16.9 KB, 32 ds_write_b16/thread); total
// staging work constant. dh twins are 512 apart (512%8==0 -> same XCD) so
// feature tiles stay L2-shared. Phase-2 math and the verified frag-major
// granule store formula unchanged except tt_tile = tch*2 + tokt.
// ---------------------------------------------------------------------------
__global__ __launch_bounds__(256, 2) void proj_kernel(
    const float* __restrict__ feature,
    const ushort_t* __restrict__ qwb, const ushort_t* __restrict__ kwb,
    const float* __restrict__ q_bias, const float* __restrict__ k_bias,
    ushort_t* __restrict__ qb, ushort_t* __restrict__ kb)
{
    int id = blockIdx.x;
    int dh = id >> 9;            // 0..1 d-half; twins id, id+512 share (b,tch)
    int inner = id & 511;
    int b   = inner & 3;
    int tch = inner >> 2;        // 0..127: token chunks of 32
    int tok0 = tch * 32;

    int t = threadIdx.x, w = t >> 6, lane = t & 63;
    int n16 = lane & 15, quad = lane >> 4;

    __shared__ ushort_t lsB[32][264];   // [tok][c 0..255] bf16, stride 264

    const float* F = feature + (size_t)(b * CC) * HWN;

    int cl = t >> 2, tg = (t & 3) * 8;   // 4 threads per c-row, 8 tokens each

    #pragma unroll
    for (int ch = 0; ch < 4; ch++) {
        const float* src = F + (size_t)(ch * 64 + cl) * HWN + tok0 + tg;
        float4 f0 = *(const float4*)(src);
        float4 f1 = *(const float4*)(src + 4);
        int c = ch * 64 + cl;
        lsB[tg + 0][c] = f2bf(f0.x); lsB[tg + 1][c] = f2bf(f0.y);
        lsB[tg + 2][c] = f2bf(f0.z); lsB[tg + 3][c] = f2bf(f0.w);
        lsB[tg + 4][c] = f2bf(f1.x); lsB[tg + 5][c] = f2bf(f1.y);
        lsB[tg + 6][c] = f2bf(f1.z); lsB[tg + 7][c] = f2bf(f1.w);
    }
    __syncthreads();    // single barrier: lsB complete

    int dw0 = dh * 128 + w * 32;
    #pragma unroll
    for (int dsub = 0; dsub < 2; dsub++) {
        int d0 = dw0 + dsub * 16;
        f32x4 accq[2], acck[2];
        #pragma unroll
        for (int i = 0; i < 2; i++) {
            accq[i] = (f32x4){0.f, 0.f, 0.f, 0.f};
            acck[i] = (f32x4){0.f, 0.f, 0.f, 0.f};
        }
        #pragma unroll
        for (int kc = 0; kc < 8; kc++) {
            size_t off = (size_t)(d0 + n16) * CC + kc * 32 + quad * 8;
            short8 aq = *(const short8*)&qwb[off];
            short8 ak = *(const short8*)&kwb[off];
            #pragma unroll
            for (int tokt = 0; tokt < 2; tokt++) {
                short8 bf = *(const short8*)&lsB[tokt * 16 + n16][kc * 32 + quad * 8];
                accq[tokt] = __builtin_amdgcn_mfma_f32_16x16x32_bf16(aq, bf, accq[tokt], 0, 0, 0);
                acck[tokt] = __builtin_amdgcn_mfma_f32_16x16x32_bf16(ak, bf, acck[tokt], 0, 0, 0);
            }
        }
        float bqv[4], bkv[4];
        #pragma unroll
        for (int r = 0; r < 4; r++) {
            bqv[r] = q_bias[d0 + quad * 4 + r] * SCQ;
            bkv[r] = k_bias[d0 + quad * 4 + r];
        }
        // frag-major store indices (verified formula)
        int kcq   = d0 >> 5;
        int quadA = ((d0 >> 4) & 1) * 2 + (quad >> 1);
        int halfo = quad & 1;
        #pragma unroll
        for (int tokt = 0; tokt < 2; tokt++) {
            ushort4 oq, ok;
            oq.x = f2bf(accq[tokt][0] + bqv[0]); oq.y = f2bf(accq[tokt][1] + bqv[1]);
            oq.z = f2bf(accq[tokt][2] + bqv[2]); oq.w = f2bf(accq[tokt][3] + bqv[3]);
            ok.x = f2bf(acck[tokt][0] + bkv[0]); ok.y = f2bf(acck[tokt][1] + bkv[1]);
            ok.z = f2bf(acck[tokt][2] + bkv[2]); ok.w = f2bf(acck[tokt][3] + bkv[3]);
            int tt_tile = tch * 2 + tokt;     // 0..255 per b
            size_t gbyte = (((size_t)(b * 256 + tt_tile) * 512) + kcq * 64 + quadA * 16 + n16) * 16
                           + halfo * 8;
            *(ushort4*)((char*)qb + gbyte) = oq;
            *(ushort4*)((char*)kb + gbyte) = ok;
        }
    }
}

// ---------------------------------------------------------------------------
// Attention (round-12 verified, VERBATIM — frozen: rounds 6/8/11/13 showed
// manual/compiler pipelining of this loop either miscomputes or loses more
// occupancy than it gains; (256,2) + in-loop kf0/kf1 is the equilibrium).
// ---------------------------------------------------------------------------
__global__ __launch_bounds__(256, 2) void attn_kernel(
    const ushort_t* __restrict__ qb, const ushort_t* __restrict__ kb,
    const float* __restrict__ flow,
    float* __restrict__ den_g, float* __restrict__ nx_g, float* __restrict__ ny_g)
{
    int id = (blockIdx.x & 7) * 128 + (blockIdx.x >> 3);   // bijective XCD swizzle
    int qt = id & 63; id >>= 6;       // 64 q-tiles of 64 rows
    int sr = id & 3;  id >>= 2;       // 4 key ranges of 1024
    int b = id;

    int t = threadIdx.x;
    int w = t >> 6, lane = t & 63;
    int n16 = lane & 15, quad = lane >> 4;

    int q0 = qt * 64;
    int s_beg = sr * 1024;

    __shared__ __align__(16) ushort_t qlds[16384];   // 32 KB: 4 q-tiles, frag-major
    __shared__ float lflow[2048];                    // 1024 vx + 1024 vy

    const float* fx = flow + (size_t)b * 2 * HWN;
    const float* fy = fx + HWN;
    #pragma unroll
    for (int i = 0; i < 4; i++) {
        lflow[t + i * 256]        = fx[s_beg + t + i * 256];
        lflow[1024 + t + i * 256] = fy[s_beg + t + i * 256];
    }

    // stage Q block (4 tiles x 512 granules x 16B = 32KB), linear copy
    {
        const char* qsrc = (const char*)qb + ((size_t)(b * 256 + (q0 >> 4)) * 512) * 16;
        char* qdst = (char*)qlds;
        #pragma unroll
        for (int i = 0; i < 8; i++)
            __builtin_amdgcn_global_load_lds(
                (const __attribute__((address_space(1))) unsigned int*)(qsrc + (i * 256 + t) * 16),
                (__attribute__((address_space(3))) unsigned int*)(qdst + (i * 256 + t) * 16),
                16, 0, 0);
    }
    __syncthreads();   // only barrier: Q + flow staged

    // K granule base for this wave's 256-key quarter
    const char* kbase = (const char*)kb
        + ((size_t)(b * 256 + (s_beg >> 4) + w * 16) * 512 + lane) * 16;
    const char* qldsb = (const char*)qlds + (size_t)lane * 16;

    float den[4], nxa[4], nya[4];
    #pragma unroll
    for (int i = 0; i < 4; i++) { den[i] = 0.f; nxa[i] = 0.f; nya[i] = 0.f; }

    for (int round = 0; round < 8; round++) {
        short8 kf0[8], kf1[8];
        #pragma unroll
        for (int kc = 0; kc < 8; kc++) {
            kf0[kc] = *(const short8*)(kbase + (round * 2 + 0) * 8192 + kc * 1024);
            kf1[kc] = *(const short8*)(kbase + (round * 2 + 1) * 8192 + kc * 1024);
        }
        int klbase = w * 256 + round * 32 + quad * 4;
        f32x4 vx0 = *(const f32x4*)&lflow[klbase];
        f32x4 vx1 = *(const f32x4*)&lflow[klbase + 16];
        f32x4 vy0 = *(const f32x4*)&lflow[1024 + klbase];
        f32x4 vy1 = *(const f32x4*)&lflow[1024 + klbase + 16];

        #pragma unroll
        for (int qtl = 0; qtl < 4; qtl++) {
            f32x4 a0 = (f32x4){0.f, 0.f, 0.f, 0.f};
            f32x4 a1 = (f32x4){0.f, 0.f, 0.f, 0.f};
            #pragma unroll
            for (int kc = 0; kc < 8; kc++) {
                short8 qf = *(const short8*)(qldsb + qtl * 8192 + kc * 1024);
                a0 = __builtin_amdgcn_mfma_f32_16x16x32_bf16(kf0[kc], qf, a0, 0, 0, 0);
                a1 = __builtin_amdgcn_mfma_f32_16x16x32_bf16(kf1[kc], qf, a1, 0, 0, 0);
            }
            float d_ = 0.f, x_ = 0.f, y_ = 0.f;
            #pragma unroll
            for (int r = 0; r < 4; r++) {
                float p0 = fexp2(a0[r]);
                float p1 = fexp2(a1[r]);
                d_ += p0 + p1;
                x_ = fmaf(p0, vx0[r], x_); x_ = fmaf(p1, vx1[r], x_);
                y_ = fmaf(p0, vy0[r], y_); y_ = fmaf(p1, vy1[r], y_);
            }
            den[qtl] += d_; nxa[qtl] += x_; nya[qtl] += y_;
        }
    }

    #pragma unroll
    for (int qtl = 0; qtl < 4; qtl++) {
        float dv = den[qtl], xv = nxa[qtl], yv = nya[qtl];
        dv += __shfl_down(dv, 32); dv += __shfl_down(dv, 16);
        xv += __shfl_down(xv, 32); xv += __shfl_down(xv, 16);
        yv += __shfl_down(yv, 32); yv += __shfl_down(yv, 16);
        if (lane < 16) {
            int qrow = q0 + qtl * 16 + n16;
            int gi = b * HWN + qrow;
            atomicAdd(&den_g[gi], dv);
            atomicAdd(&nx_g[gi],  xv);
            atomicAdd(&ny_g[gi],  yv);
        }
    }
}

// ---------------------------------------------------------------------------
__global__ __launch_bounds__(256) void finalize_kernel(
    const float* __restrict__ den_g, const float* __restrict__ nx_g,
    const float* __restrict__ ny_g, float* __restrict__ out)
{
    int idx = blockIdx.x * 256 + threadIdx.x;  // b*HW + n
    int b = idx >> 12, n = idx & 4095;
    float inv = 1.0f / den_g[idx];
    out[(size_t)b * 2 * HWN + n]       = nx_g[idx] * inv;
    out[(size_t)b * 2 * HWN + HWN + n] = ny_g[idx] * inv;
}

extern "C" void kernel_launch(void* const* d_in, const int* in_sizes, int n_in,
                              void* d_out, int out_size, void* d_ws, size_t ws_size,
                              hipStream_t stream) {
    const float* feature = (const float*)d_in[0];
    const float* flow    = (const float*)d_in[1];
    const float* q_w     = (const float*)d_in[2];
    const float* q_b     = (const float*)d_in[3];
    const float* k_w     = (const float*)d_in[4];
    const float* k_b     = (const float*)d_in[5];
    float* out = (float*)d_out;

    ushort_t* qbuf = (ushort_t*)d_ws;                     // [NTOK][CC] bf16, frag-major
    ushort_t* kbuf = qbuf + (size_t)NTOK * CC;            // [NTOK][CC] bf16, frag-major
    float* den = (float*)(kbuf + (size_t)NTOK * CC);      // [NTOK]
    float* nx  = den + NTOK;
    float* ny  = nx + NTOK;
    ushort_t* qwb = (ushort_t*)(ny + NTOK);               // [CC][CC] bf16 (pre-scaled)
    ushort_t* kwb = qwb + (size_t)CC * CC;                // [CC][CC] bf16

    wprep_kernel<<<64, 256, 0, stream>>>(q_w, k_w, qwb, kwb, den);  // + zero den/nx/ny
    proj_kernel<<<1024, 256, 0, stream>>>(feature, qwb, kwb, q_b, k_b, qbuf, kbuf);
    attn_kernel<<<1024, 256, 0, stream>>>(qbuf, kbuf, flow, den, nx, ny);
    finalize_kernel<<<64, 256, 0, stream>>>(den, nx, ny, out);
}

// Round 16
// 129.524 us; speedup vs baseline: 1.1848x; 1.0486x over previous
//
#include <hip/hip_runtime.h>
#include <math.h>

#define BB 4
#define CC 256
#define HWN 4096
#define NTOK 16384                 // BB*HWN
#define SCQ 0.09016844136f         // (1/sqrt(256)) * log2(e)

typedef __attribute__((ext_vector_type(8))) short short8;
typedef __attribute__((ext_vector_type(4))) float f32x4;
typedef unsigned short ushort_t;

__device__ __forceinline__ ushort_t f2bf(float f) {
    unsigned int u = __float_as_uint(f);
    unsigned int r = (u + 0x7FFFu + ((u >> 16) & 1u)) >> 16;   // RNE
    return (ushort_t)r;
}
__device__ __forceinline__ unsigned int pack2(float a, float b) {
    return (unsigned int)f2bf(a) | ((unsigned int)f2bf(b) << 16);
}
__device__ __forceinline__ float fexp2(float x) {
#if __has_builtin(__builtin_amdgcn_exp2f)
    return __builtin_amdgcn_exp2f(x);     // single v_exp_f32
#else
    return exp2f(x);
#endif
}

// ---------------------------------------------------------------------------
// wprep (verified): convert q_w (pre-scaled by SCQ) and k_w to bf16;
// zero den/nx/ny.
// ---------------------------------------------------------------------------
__global__ __launch_bounds__(256) void wprep_kernel(
    const float* __restrict__ q_w, const float* __restrict__ k_w,
    ushort_t* __restrict__ qwb, ushort_t* __restrict__ kwb,
    float* __restrict__ zbuf)
{
    int t = blockIdx.x * 256 + threadIdx.x;          // grid 64 -> 16384 threads
    float4 q4 = *(const float4*)&q_w[(size_t)t * 4];
    float4 k4 = *(const float4*)&k_w[(size_t)t * 4];
    unsigned long long qo = (unsigned long long)pack2(q4.x * SCQ, q4.y * SCQ)
                          | ((unsigned long long)pack2(q4.z * SCQ, q4.w * SCQ) << 32);
    unsigned long long ko = (unsigned long long)pack2(k4.x, k4.y)
                          | ((unsigned long long)pack2(k4.z, k4.w) << 32);
    *(unsigned long long*)&qwb[(size_t)t * 4] = qo;
    *(unsigned long long*)&kwb[(size_t)t * 4] = ko;
    zbuf[t] = 0.f; zbuf[t + NTOK] = 0.f; zbuf[t + 2 * NTOK] = 0.f;
}

// ---------------------------------------------------------------------------
// Fused projection v2 (round-12 verified, verbatim — the proj equilibrium:
// 64-token x 128-d; R0 showed bigger tiles starve occupancy, R15 showed
// smaller tiles double weight traffic). Single-barrier staging converts
// fp32->bf16 directly into transposed lsB; frag-major granule stores.
// ---------------------------------------------------------------------------
__global__ __launch_bounds__(256, 2) void proj_kernel(
    const float* __restrict__ feature,
    const ushort_t* __restrict__ qwb, const ushort_t* __restrict__ kwb,
    const float* __restrict__ q_bias, const float* __restrict__ k_bias,
    ushort_t* __restrict__ qb, ushort_t* __restrict__ kb)
{
    int id = blockIdx.x;
    int dh = id >> 8;            // 0..1: twin blocks 256 apart share (b,tt)
    id &= 255;
    int tt = id & 63;
    int b  = id >> 6;
    int tok0 = tt * 64;

    int t = threadIdx.x, w = t >> 6, lane = t & 63;
    int n16 = lane & 15, quad = lane >> 4;

    __shared__ ushort_t lsB[64][264];   // [tok][c 0..255] bf16, stride 264

    const float* F = feature + (size_t)(b * CC) * HWN;

    int cl = t >> 2, tg = (t & 3) * 16;

    #pragma unroll
    for (int ch = 0; ch < 4; ch++) {
        const float* src = F + (size_t)(ch * 64 + cl) * HWN + tok0 + tg;
        float4 f0 = *(const float4*)(src);
        float4 f1 = *(const float4*)(src + 4);
        float4 f2 = *(const float4*)(src + 8);
        float4 f3 = *(const float4*)(src + 12);
        int c = ch * 64 + cl;
        lsB[tg + 0][c]  = f2bf(f0.x); lsB[tg + 1][c]  = f2bf(f0.y);
        lsB[tg + 2][c]  = f2bf(f0.z); lsB[tg + 3][c]  = f2bf(f0.w);
        lsB[tg + 4][c]  = f2bf(f1.x); lsB[tg + 5][c]  = f2bf(f1.y);
        lsB[tg + 6][c]  = f2bf(f1.z); lsB[tg + 7][c]  = f2bf(f1.w);
        lsB[tg + 8][c]  = f2bf(f2.x); lsB[tg + 9][c]  = f2bf(f2.y);
        lsB[tg + 10][c] = f2bf(f2.z); lsB[tg + 11][c] = f2bf(f2.w);
        lsB[tg + 12][c] = f2bf(f3.x); lsB[tg + 13][c] = f2bf(f3.y);
        lsB[tg + 14][c] = f2bf(f3.z); lsB[tg + 15][c] = f2bf(f3.w);
    }
    __syncthreads();    // single barrier: lsB complete

    int dw0 = dh * 128 + w * 32;
    #pragma unroll
    for (int dsub = 0; dsub < 2; dsub++) {
        int d0 = dw0 + dsub * 16;
        f32x4 accq[4], acck[4];
        #pragma unroll
        for (int i = 0; i < 4; i++) {
            accq[i] = (f32x4){0.f, 0.f, 0.f, 0.f};
            acck[i] = (f32x4){0.f, 0.f, 0.f, 0.f};
        }
        #pragma unroll
        for (int kc = 0; kc < 8; kc++) {
            size_t off = (size_t)(d0 + n16) * CC + kc * 32 + quad * 8;
            short8 aq = *(const short8*)&qwb[off];
            short8 ak = *(const short8*)&kwb[off];
            #pragma unroll
            for (int tokt = 0; tokt < 4; tokt++) {
                short8 bf = *(const short8*)&lsB[tokt * 16 + n16][kc * 32 + quad * 8];
                accq[tokt] = __builtin_amdgcn_mfma_f32_16x16x32_bf16(aq, bf, accq[tokt], 0, 0, 0);
                acck[tokt] = __builtin_amdgcn_mfma_f32_16x16x32_bf16(ak, bf, acck[tokt], 0, 0, 0);
            }
        }
        float bqv[4], bkv[4];
        #pragma unroll
        for (int r = 0; r < 4; r++) {
            bqv[r] = q_bias[d0 + quad * 4 + r] * SCQ;
            bkv[r] = k_bias[d0 + quad * 4 + r];
        }
        // frag-major store indices (verified formula)
        int kcq   = d0 >> 5;
        int quadA = ((d0 >> 4) & 1) * 2 + (quad >> 1);
        int halfo = quad & 1;
        #pragma unroll
        for (int tokt = 0; tokt < 4; tokt++) {
            ushort4 oq, ok;
            oq.x = f2bf(accq[tokt][0] + bqv[0]); oq.y = f2bf(accq[tokt][1] + bqv[1]);
            oq.z = f2bf(accq[tokt][2] + bqv[2]); oq.w = f2bf(accq[tokt][3] + bqv[3]);
            ok.x = f2bf(acck[tokt][0] + bkv[0]); ok.y = f2bf(acck[tokt][1] + bkv[1]);
            ok.z = f2bf(acck[tokt][2] + bkv[2]); ok.w = f2bf(acck[tokt][3] + bkv[3]);
            int tt_tile = tt * 4 + tokt;
            size_t gbyte = (((size_t)(b * 256 + tt_tile) * 512) + kcq * 64 + quadA * 16 + n16) * 16
                           + halfo * 8;
            *(ushort4*)((char*)qb + gbyte) = oq;
            *(ushort4*)((char*)kb + gbyte) = ok;
        }
    }
}

// ---------------------------------------------------------------------------
// Attention (round-12 verified, VERBATIM — frozen equilibrium: manual
// register pipelining miscomputes (R6/R8/R11/R13), compiler pipelining
// trades occupancy at a net loss (R14: VGPR 172, occ 10%, +21us).
// Block = (b, 64-q, 1024-key), 4 waves = key-quarters; wave = 64q x 256keys.
// Q staged via global_load_lds once, read lane-contiguous in the K loop;
// K streamed L2->regs per 32-key round; atomic merge.
// ---------------------------------------------------------------------------
__global__ __launch_bounds__(256, 2) void attn_kernel(
    const ushort_t* __restrict__ qb, const ushort_t* __restrict__ kb,
    const float* __restrict__ flow,
    float* __restrict__ den_g, float* __restrict__ nx_g, float* __restrict__ ny_g)
{
    int id = (blockIdx.x & 7) * 128 + (blockIdx.x >> 3);   // bijective XCD swizzle
    int qt = id & 63; id >>= 6;       // 64 q-tiles of 64 rows
    int sr = id & 3;  id >>= 2;       // 4 key ranges of 1024
    int b = id;

    int t = threadIdx.x;
    int w = t >> 6, lane = t & 63;
    int n16 = lane & 15, quad = lane >> 4;

    int q0 = qt * 64;
    int s_beg = sr * 1024;

    __shared__ __align__(16) ushort_t qlds[16384];   // 32 KB: 4 q-tiles, frag-major
    __shared__ float lflow[2048];                    // 1024 vx + 1024 vy

    const float* fx = flow + (size_t)b * 2 * HWN;
    const float* fy = fx + HWN;
    #pragma unroll
    for (int i = 0; i < 4; i++) {
        lflow[t + i * 256]        = fx[s_beg + t + i * 256];
        lflow[1024 + t + i * 256] = fy[s_beg + t + i * 256];
    }

    // stage Q block (4 tiles x 512 granules x 16B = 32KB), linear copy
    {
        const char* qsrc = (const char*)qb + ((size_t)(b * 256 + (q0 >> 4)) * 512) * 16;
        char* qdst = (char*)qlds;
        #pragma unroll
        for (int i = 0; i < 8; i++)
            __builtin_amdgcn_global_load_lds(
                (const __attribute__((address_space(1))) unsigned int*)(qsrc + (i * 256 + t) * 16),
                (__attribute__((address_space(3))) unsigned int*)(qdst + (i * 256 + t) * 16),
                16, 0, 0);
    }
    __syncthreads();   // only barrier: Q + flow staged

    // K granule base for this wave's 256-key quarter
    const char* kbase = (const char*)kb
        + ((size_t)(b * 256 + (s_beg >> 4) + w * 16) * 512 + lane) * 16;
    const char* qldsb = (const char*)qlds + (size_t)lane * 16;

    float den[4], nxa[4], nya[4];
    #pragma unroll
    for (int i = 0; i < 4; i++) { den[i] = 0.f; nxa[i] = 0.f; nya[i] = 0.f; }

    for (int round = 0; round < 8; round++) {
        short8 kf0[8], kf1[8];
        #pragma unroll
        for (int kc = 0; kc < 8; kc++) {
            kf0[kc] = *(const short8*)(kbase + (round * 2 + 0) * 8192 + kc * 1024);
            kf1[kc] = *(const short8*)(kbase + (round * 2 + 1) * 8192 + kc * 1024);
        }
        int klbase = w * 256 + round * 32 + quad * 4;
        f32x4 vx0 = *(const f32x4*)&lflow[klbase];
        f32x4 vx1 = *(const f32x4*)&lflow[klbase + 16];
        f32x4 vy0 = *(const f32x4*)&lflow[1024 + klbase];
        f32x4 vy1 = *(const f32x4*)&lflow[1024 + klbase + 16];

        #pragma unroll
        for (int qtl = 0; qtl < 4; qtl++) {
            f32x4 a0 = (f32x4){0.f, 0.f, 0.f, 0.f};
            f32x4 a1 = (f32x4){0.f, 0.f, 0.f, 0.f};
            #pragma unroll
            for (int kc = 0; kc < 8; kc++) {
                short8 qf = *(const short8*)(qldsb + qtl * 8192 + kc * 1024);
                a0 = __builtin_amdgcn_mfma_f32_16x16x32_bf16(kf0[kc], qf, a0, 0, 0, 0);
                a1 = __builtin_amdgcn_mfma_f32_16x16x32_bf16(kf1[kc], qf, a1, 0, 0, 0);
            }
            float d_ = 0.f, x_ = 0.f, y_ = 0.f;
            #pragma unroll
            for (int r = 0; r < 4; r++) {
                float p0 = fexp2(a0[r]);
                float p1 = fexp2(a1[r]);
                d_ += p0 + p1;
                x_ = fmaf(p0, vx0[r], x_); x_ = fmaf(p1, vx1[r], x_);
                y_ = fmaf(p0, vy0[r], y_); y_ = fmaf(p1, vy1[r], y_);
            }
            den[qtl] += d_; nxa[qtl] += x_; nya[qtl] += y_;
        }
    }

    #pragma unroll
    for (int qtl = 0; qtl < 4; qtl++) {
        float dv = den[qtl], xv = nxa[qtl], yv = nya[qtl];
        dv += __shfl_down(dv, 32); dv += __shfl_down(dv, 16);
        xv += __shfl_down(xv, 32); xv += __shfl_down(xv, 16);
        yv += __shfl_down(yv, 32); yv += __shfl_down(yv, 16);
        if (lane < 16) {
            int qrow = q0 + qtl * 16 + n16;
            int gi = b * HWN + qrow;
            atomicAdd(&den_g[gi], dv);
            atomicAdd(&nx_g[gi],  xv);
            atomicAdd(&ny_g[gi],  yv);
        }
    }
}

// ---------------------------------------------------------------------------
__global__ __launch_bounds__(256) void finalize_kernel(
    const float* __restrict__ den_g, const float* __restrict__ nx_g,
    const float* __restrict__ ny_g, float* __restrict__ out)
{
    int idx = blockIdx.x * 256 + threadIdx.x;  // b*HW + n
    int b = idx >> 12, n = idx & 4095;
    float inv = 1.0f / den_g[idx];
    out[(size_t)b * 2 * HWN + n]       = nx_g[idx] * inv;
    out[(size_t)b * 2 * HWN + HWN + n] = ny_g[idx] * inv;
}

extern "C" void kernel_launch(void* const* d_in, const int* in_sizes, int n_in,
                              void* d_out, int out_size, void* d_ws, size_t ws_size,
                              hipStream_t stream) {
    const float* feature = (const float*)d_in[0];
    const float* flow    = (const float*)d_in[1];
    const float* q_w     = (const float*)d_in[2];
    const float* q_b     = (const float*)d_in[3];
    const float* k_w     = (const float*)d_in[4];
    const float* k_b     = (const float*)d_in[5];
    float* out = (float*)d_out;

    ushort_t* qbuf = (ushort_t*)d_ws;                     // [NTOK][CC] bf16, frag-major
    ushort_t* kbuf = qbuf + (size_t)NTOK * CC;            // [NTOK][CC] bf16, frag-major
    float* den = (float*)(kbuf + (size_t)NTOK * CC);      // [NTOK]
    float* nx  = den + NTOK;
    float* ny  = nx + NTOK;
    ushort_t* qwb = (ushort_t*)(ny + NTOK);               // [CC][CC] bf16 (pre-scaled)
    ushort_t* kwb = qwb + (size_t)CC * CC;                // [CC][CC] bf16

    wprep_kernel<<<64, 256, 0, stream>>>(q_w, k_w, qwb, kwb, den);  // + zero den/nx/ny
    proj_kernel<<<512, 256, 0, stream>>>(feature, qwb, kwb, q_b, k_b, qbuf, kbuf);
    attn_kernel<<<1024, 256, 0, stream>>>(qbuf, kbuf, flow, den, nx, ny);
    finalize_kernel<<<64, 256, 0, stream>>>(den, nx, ny, out);
}

// Round 17
// 125.785 us; speedup vs baseline: 1.2200x; 1.0297x over previous
//
#include <hip/hip_runtime.h>
#include <math.h>

#define BB 4
#define CC 256
#define HWN 4096
#define NTOK 16384                 // BB*HWN
#define SCQ 0.09016844136f         // (1/sqrt(256)) * log2(e)

typedef __attribute__((ext_vector_type(8))) short short8;
typedef __attribute__((ext_vector_type(4))) float f32x4;
typedef unsigned short ushort_t;

__device__ __forceinline__ ushort_t f2bf(float f) {
    unsigned int u = __float_as_uint(f);
    unsigned int r = (u + 0x7FFFu + ((u >> 16) & 1u)) >> 16;   // RNE
    return (ushort_t)r;
}
__device__ __forceinline__ unsigned int pack2(float a, float b) {
    return (unsigned int)f2bf(a) | ((unsigned int)f2bf(b) << 16);
}
__device__ __forceinline__ float fexp2(float x) {
#if __has_builtin(__builtin_amdgcn_exp2f)
    return __builtin_amdgcn_exp2f(x);     // single v_exp_f32
#else
    return exp2f(x);
#endif
}

// ---------------------------------------------------------------------------
// wprep (verified): convert q_w (pre-scaled by SCQ) and k_w to bf16;
// zero den/nx/ny.
// ---------------------------------------------------------------------------
__global__ __launch_bounds__(256) void wprep_kernel(
    const float* __restrict__ q_w, const float* __restrict__ k_w,
    ushort_t* __restrict__ qwb, ushort_t* __restrict__ kwb,
    float* __restrict__ zbuf)
{
    int t = blockIdx.x * 256 + threadIdx.x;          // grid 64 -> 16384 threads
    float4 q4 = *(const float4*)&q_w[(size_t)t * 4];
    float4 k4 = *(const float4*)&k_w[(size_t)t * 4];
    unsigned long long qo = (unsigned long long)pack2(q4.x * SCQ, q4.y * SCQ)
                          | ((unsigned long long)pack2(q4.z * SCQ, q4.w * SCQ) << 32);
    unsigned long long ko = (unsigned long long)pack2(k4.x, k4.y)
                          | ((unsigned long long)pack2(k4.z, k4.w) << 32);
    *(unsigned long long*)&qwb[(size_t)t * 4] = qo;
    *(unsigned long long*)&kwb[(size_t)t * 4] = ko;
    zbuf[t] = 0.f; zbuf[t + NTOK] = 0.f; zbuf[t + 2 * NTOK] = 0.f;
}

// ---------------------------------------------------------------------------
// Fused projection v2 (round-12/16 verified, verbatim — proj equilibrium:
// 64-token x 128-d). Single-barrier staging converts fp32->bf16 directly
// into transposed lsB; frag-major granule stores.
// ---------------------------------------------------------------------------
__global__ __launch_bounds__(256, 2) void proj_kernel(
    const float* __restrict__ feature,
    const ushort_t* __restrict__ qwb, const ushort_t* __restrict__ kwb,
    const float* __restrict__ q_bias, const float* __restrict__ k_bias,
    ushort_t* __restrict__ qb, ushort_t* __restrict__ kb)
{
    int id = blockIdx.x;
    int dh = id >> 8;            // 0..1: twin blocks 256 apart share (b,tt)
    id &= 255;
    int tt = id & 63;
    int b  = id >> 6;
    int tok0 = tt * 64;

    int t = threadIdx.x, w = t >> 6, lane = t & 63;
    int n16 = lane & 15, quad = lane >> 4;

    __shared__ ushort_t lsB[64][264];   // [tok][c 0..255] bf16, stride 264

    const float* F = feature + (size_t)(b * CC) * HWN;

    int cl = t >> 2, tg = (t & 3) * 16;

    #pragma unroll
    for (int ch = 0; ch < 4; ch++) {
        const float* src = F + (size_t)(ch * 64 + cl) * HWN + tok0 + tg;
        float4 f0 = *(const float4*)(src);
        float4 f1 = *(const float4*)(src + 4);
        float4 f2 = *(const float4*)(src + 8);
        float4 f3 = *(const float4*)(src + 12);
        int c = ch * 64 + cl;
        lsB[tg + 0][c]  = f2bf(f0.x); lsB[tg + 1][c]  = f2bf(f0.y);
        lsB[tg + 2][c]  = f2bf(f0.z); lsB[tg + 3][c]  = f2bf(f0.w);
        lsB[tg + 4][c]  = f2bf(f1.x); lsB[tg + 5][c]  = f2bf(f1.y);
        lsB[tg + 6][c]  = f2bf(f1.z); lsB[tg + 7][c]  = f2bf(f1.w);
        lsB[tg + 8][c]  = f2bf(f2.x); lsB[tg + 9][c]  = f2bf(f2.y);
        lsB[tg + 10][c] = f2bf(f2.z); lsB[tg + 11][c] = f2bf(f2.w);
        lsB[tg + 12][c] = f2bf(f3.x); lsB[tg + 13][c] = f2bf(f3.y);
        lsB[tg + 14][c] = f2bf(f3.z); lsB[tg + 15][c] = f2bf(f3.w);
    }
    __syncthreads();    // single barrier: lsB complete

    int dw0 = dh * 128 + w * 32;
    #pragma unroll
    for (int dsub = 0; dsub < 2; dsub++) {
        int d0 = dw0 + dsub * 16;
        f32x4 accq[4], acck[4];
        #pragma unroll
        for (int i = 0; i < 4; i++) {
            accq[i] = (f32x4){0.f, 0.f, 0.f, 0.f};
            acck[i] = (f32x4){0.f, 0.f, 0.f, 0.f};
        }
        #pragma unroll
        for (int kc = 0; kc < 8; kc++) {
            size_t off = (size_t)(d0 + n16) * CC + kc * 32 + quad * 8;
            short8 aq = *(const short8*)&qwb[off];
            short8 ak = *(const short8*)&kwb[off];
            #pragma unroll
            for (int tokt = 0; tokt < 4; tokt++) {
                short8 bf = *(const short8*)&lsB[tokt * 16 + n16][kc * 32 + quad * 8];
                accq[tokt] = __builtin_amdgcn_mfma_f32_16x16x32_bf16(aq, bf, accq[tokt], 0, 0, 0);
                acck[tokt] = __builtin_amdgcn_mfma_f32_16x16x32_bf16(ak, bf, acck[tokt], 0, 0, 0);
            }
        }
        float bqv[4], bkv[4];
        #pragma unroll
        for (int r = 0; r < 4; r++) {
            bqv[r] = q_bias[d0 + quad * 4 + r] * SCQ;
            bkv[r] = k_bias[d0 + quad * 4 + r];
        }
        // frag-major store indices (verified formula)
        int kcq   = d0 >> 5;
        int quadA = ((d0 >> 4) & 1) * 2 + (quad >> 1);
        int halfo = quad & 1;
        #pragma unroll
        for (int tokt = 0; tokt < 4; tokt++) {
            ushort4 oq, ok;
            oq.x = f2bf(accq[tokt][0] + bqv[0]); oq.y = f2bf(accq[tokt][1] + bqv[1]);
            oq.z = f2bf(accq[tokt][2] + bqv[2]); oq.w = f2bf(accq[tokt][3] + bqv[3]);
            ok.x = f2bf(acck[tokt][0] + bkv[0]); ok.y = f2bf(acck[tokt][1] + bkv[1]);
            ok.z = f2bf(acck[tokt][2] + bkv[2]); ok.w = f2bf(acck[tokt][3] + bkv[3]);
            int tt_tile = tt * 4 + tokt;
            size_t gbyte = (((size_t)(b * 256 + tt_tile) * 512) + kcq * 64 + quadA * 16 + n16) * 16
                           + halfo * 8;
            *(ushort4*)((char*)qb + gbyte) = oq;
            *(ushort4*)((char*)kb + gbyte) = ok;
        }
    }
}

// ---------------------------------------------------------------------------
// Attention v10 = round-12/16 verified kernel with ONE parameter change:
// sr-split 4 -> 2 (block = (b, 64-q, 2048-key), grid 512). Per-block fixed
// costs (flow stage, Q stage, barrier, atomics) amortize over 2x compute;
// total Q re-staging 32 MB -> 16 MB; atomics halved. K-loop body, wave
// partition, addressing pattern, epilogue verbatim (rounds 8 -> 16,
// lflow doubled, kbase w*16 -> w*32 tiles). LDS 48 KB.
// ---------------------------------------------------------------------------
__global__ __launch_bounds__(256, 2) void attn_kernel(
    const ushort_t* __restrict__ qb, const ushort_t* __restrict__ kb,
    const float* __restrict__ flow,
    float* __restrict__ den_g, float* __restrict__ nx_g, float* __restrict__ ny_g)
{
    int id = (blockIdx.x & 7) * 64 + (blockIdx.x >> 3);   // 512 = 8*64, bijective
    int qt = id & 63; id >>= 6;       // 64 q-tiles of 64 rows
    int sr = id & 1;  id >>= 1;       // 2 key ranges of 2048
    int b = id;

    int t = threadIdx.x;
    int w = t >> 6, lane = t & 63;
    int n16 = lane & 15, quad = lane >> 4;

    int q0 = qt * 64;
    int s_beg = sr * 2048;

    __shared__ __align__(16) ushort_t qlds[16384];   // 32 KB: 4 q-tiles, frag-major
    __shared__ float lflow[4096];                    // 2048 vx + 2048 vy

    const float* fx = flow + (size_t)b * 2 * HWN;
    const float* fy = fx + HWN;
    #pragma unroll
    for (int i = 0; i < 8; i++) {
        lflow[t + i * 256]        = fx[s_beg + t + i * 256];
        lflow[2048 + t + i * 256] = fy[s_beg + t + i * 256];
    }

    // stage Q block (4 tiles x 512 granules x 16B = 32KB), linear copy
    {
        const char* qsrc = (const char*)qb + ((size_t)(b * 256 + (q0 >> 4)) * 512) * 16;
        char* qdst = (char*)qlds;
        #pragma unroll
        for (int i = 0; i < 8; i++)
            __builtin_amdgcn_global_load_lds(
                (const __attribute__((address_space(1))) unsigned int*)(qsrc + (i * 256 + t) * 16),
                (__attribute__((address_space(3))) unsigned int*)(qdst + (i * 256 + t) * 16),
                16, 0, 0);
    }
    __syncthreads();   // only barrier: Q + flow staged

    // K granule base for this wave's 512-key quarter (32 x 16-key tiles)
    const char* kbase = (const char*)kb
        + ((size_t)(b * 256 + (s_beg >> 4) + w * 32) * 512 + lane) * 16;
    const char* qldsb = (const char*)qlds + (size_t)lane * 16;

    float den[4], nxa[4], nya[4];
    #pragma unroll
    for (int i = 0; i < 4; i++) { den[i] = 0.f; nxa[i] = 0.f; nya[i] = 0.f; }

    for (int round = 0; round < 16; round++) {
        short8 kf0[8], kf1[8];
        #pragma unroll
        for (int kc = 0; kc < 8; kc++) {
            kf0[kc] = *(const short8*)(kbase + (round * 2 + 0) * 8192 + kc * 1024);
            kf1[kc] = *(const short8*)(kbase + (round * 2 + 1) * 8192 + kc * 1024);
        }
        int klbase = w * 512 + round * 32 + quad * 4;
        f32x4 vx0 = *(const f32x4*)&lflow[klbase];
        f32x4 vx1 = *(const f32x4*)&lflow[klbase + 16];
        f32x4 vy0 = *(const f32x4*)&lflow[2048 + klbase];
        f32x4 vy1 = *(const f32x4*)&lflow[2048 + klbase + 16];

        #pragma unroll
        for (int qtl = 0; qtl < 4; qtl++) {
            f32x4 a0 = (f32x4){0.f, 0.f, 0.f, 0.f};
            f32x4 a1 = (f32x4){0.f, 0.f, 0.f, 0.f};
            #pragma unroll
            for (int kc = 0; kc < 8; kc++) {
                short8 qf = *(const short8*)(qldsb + qtl * 8192 + kc * 1024);
                a0 = __builtin_amdgcn_mfma_f32_16x16x32_bf16(kf0[kc], qf, a0, 0, 0, 0);
                a1 = __builtin_amdgcn_mfma_f32_16x16x32_bf16(kf1[kc], qf, a1, 0, 0, 0);
            }
            float d_ = 0.f, x_ = 0.f, y_ = 0.f;
            #pragma unroll
            for (int r = 0; r < 4; r++) {
                float p0 = fexp2(a0[r]);
                float p1 = fexp2(a1[r]);
                d_ += p0 + p1;
                x_ = fmaf(p0, vx0[r], x_); x_ = fmaf(p1, vx1[r], x_);
                y_ = fmaf(p0, vy0[r], y_); y_ = fmaf(p1, vy1[r], y_);
            }
            den[qtl] += d_; nxa[qtl] += x_; nya[qtl] += y_;
        }
    }

    #pragma unroll
    for (int qtl = 0; qtl < 4; qtl++) {
        float dv = den[qtl], xv = nxa[qtl], yv = nya[qtl];
        dv += __shfl_down(dv, 32); dv += __shfl_down(dv, 16);
        xv += __shfl_down(xv, 32); xv += __shfl_down(xv, 16);
        yv += __shfl_down(yv, 32); yv += __shfl_down(yv, 16);
        if (lane < 16) {
            int qrow = q0 + qtl * 16 + n16;
            int gi = b * HWN + qrow;
            atomicAdd(&den_g[gi], dv);
            atomicAdd(&nx_g[gi],  xv);
            atomicAdd(&ny_g[gi],  yv);
        }
    }
}

// ---------------------------------------------------------------------------
__global__ __launch_bounds__(256) void finalize_kernel(
    const float* __restrict__ den_g, const float* __restrict__ nx_g,
    const float* __restrict__ ny_g, float* __restrict__ out)
{
    int idx = blockIdx.x * 256 + threadIdx.x;  // b*HW + n
    int b = idx >> 12, n = idx & 4095;
    float inv = 1.0f / den_g[idx];
    out[(size_t)b * 2 * HWN + n]       = nx_g[idx] * inv;
    out[(size_t)b * 2 * HWN + HWN + n] = ny_g[idx] * inv;
}

extern "C" void kernel_launch(void* const* d_in, const int* in_sizes, int n_in,
                              void* d_out, int out_size, void* d_ws, size_t ws_size,
                              hipStream_t stream) {
    const float* feature = (const float*)d_in[0];
    const float* flow    = (const float*)d_in[1];
    const float* q_w     = (const float*)d_in[2];
    const float* q_b     = (const float*)d_in[3];
    const float* k_w     = (const float*)d_in[4];
    const float* k_b     = (const float*)d_in[5];
    float* out = (float*)d_out;

    ushort_t* qbuf = (ushort_t*)d_ws;                     // [NTOK][CC] bf16, frag-major
    ushort_t* kbuf = qbuf + (size_t)NTOK * CC;            // [NTOK][CC] bf16, frag-major
    float* den = (float*)(kbuf + (size_t)NTOK * CC);      // [NTOK]
    float* nx  = den + NTOK;
    float* ny  = nx + NTOK;
    ushort_t* qwb = (ushort_t*)(ny + NTOK);               // [CC][CC] bf16 (pre-scaled)
    ushort_t* kwb = qwb + (size_t)CC * CC;                // [CC][CC] bf16

    wprep_kernel<<<64, 256, 0, stream>>>(q_w, k_w, qwb, kwb, den);  // + zero den/nx/ny
    proj_kernel<<<512, 256, 0, stream>>>(feature, qwb, kwb, q_b, k_b, qbuf, kbuf);
    attn_kernel<<<512, 256, 0, stream>>>(qbuf, kbuf, flow, den, nx, ny);
    finalize_kernel<<<64, 256, 0, stream>>>(den, nx, ny, out);
}